// Round 1
// baseline (8490.562 us; speedup 1.0000x reference)
//
#include <hip/hip_runtime.h>

// LTC scan: one workgroup per batch item b (B=64 -> 64 WGs, 1 CU each).
// 512 threads = 8 waves: thread (j = tid&255, half = tid>>8) owns half-row
// W_rec[j, 128*half : 128*half+128] (128 VGPRs) and W_in[j, 64*half : +64]
// (64 VGPRs). h lives in LDS (wave-uniform broadcast reads). Two barriers
// per layer; x(t+1) prefetched to regs early, staged to LDS in the idle
// finalize phase.

__device__ __forceinline__ float fast_tanh(float z) {
    // 1 - 2/(e^{2z}+1); inf-safe at both ends (e=inf -> 1, e=0 -> -1)
    float e = __expf(2.0f * z);
    return 1.0f - 2.0f / (e + 1.0f);
}

__global__ void __launch_bounds__(512, 2)
ltc_scan_kernel(const float* __restrict__ x,       // [B,T,I]
                const float* __restrict__ W_in,    // [H,I]
                const float* __restrict__ b_in,    // [H]
                const float* __restrict__ W_rec,   // [H,H]
                const float* __restrict__ b_rec,   // [H]
                const float* __restrict__ tau,     // [H]
                const int*   __restrict__ num_layers,
                float*       __restrict__ out,     // [B,H]
                int T)
{
    constexpr int H = 256;
    constexpr int I = 128;
    const int b    = blockIdx.x;
    const int tid  = threadIdx.x;
    const int j    = tid & (H - 1);
    const int half = tid >> 8;            // 0 or 1
    const int L    = num_layers[0];

    __shared__ float h_lds[H];
    __shared__ float xs[I];
    __shared__ float prec[H];
    __shared__ float pin[H];

    // ---- load per-thread weight slices into registers (one-time) ----
    float wrec[128];
#pragma unroll
    for (int i = 0; i < 128; i += 4) {
        float4 v = *(const float4*)&W_rec[j * H + half * 128 + i];
        wrec[i] = v.x; wrec[i+1] = v.y; wrec[i+2] = v.z; wrec[i+3] = v.w;
    }
    float win[64];
#pragma unroll
    for (int i = 0; i < 64; i += 4) {
        float4 v = *(const float4*)&W_in[j * I + half * 64 + i];
        win[i] = v.x; win[i+1] = v.y; win[i+2] = v.z; win[i+3] = v.w;
    }
    const float bin_j  = b_in[j];
    const float brec_j = b_rec[j];
    const float s_j    = 0.1f / fminf(fmaxf(tau[j], 0.1f), 5.0f);

    float hj = 0.0f;                      // half0 thread j owns h[j]
    if (half == 0) h_lds[j] = 0.0f;
    const float* xb = x + (size_t)b * T * I;
    if (tid < I) xs[tid] = xb[tid];       // stage x(0)
    __syncthreads();

    float xnext = 0.0f;
    float xtj   = 0.0f;                   // half0: input projection, reused across layers

    for (int t = 0; t < T; ++t) {
        // issue x(t+1) global load early; consumed at last-layer finalize
        const bool pf = (half == 1) && (j < I) && (t + 1 < T);
        if (pf) xnext = xb[(size_t)(t + 1) * I + j];

        for (int l = 0; l < L; ++l) {
            // ---- compute phase: recurrent half-dot (+ input half-dot at l==0) ----
            float pr0 = 0.f, pr1 = 0.f, pr2 = 0.f, pr3 = 0.f;
            const float* hb = &h_lds[half * 128];
#pragma unroll
            for (int i = 0; i < 128; i += 16) {
                float4 a0 = *(const float4*)&hb[i];
                float4 a1 = *(const float4*)&hb[i+4];
                float4 a2 = *(const float4*)&hb[i+8];
                float4 a3 = *(const float4*)&hb[i+12];
                pr0 += wrec[i+0]*a0.x  + wrec[i+1]*a0.y  + wrec[i+2]*a0.z  + wrec[i+3]*a0.w;
                pr1 += wrec[i+4]*a1.x  + wrec[i+5]*a1.y  + wrec[i+6]*a1.z  + wrec[i+7]*a1.w;
                pr2 += wrec[i+8]*a2.x  + wrec[i+9]*a2.y  + wrec[i+10]*a2.z + wrec[i+11]*a2.w;
                pr3 += wrec[i+12]*a3.x + wrec[i+13]*a3.y + wrec[i+14]*a3.z + wrec[i+15]*a3.w;
            }
            float pr = (pr0 + pr1) + (pr2 + pr3);

            float px = 0.0f;
            if (l == 0) {
                float q0 = 0.f, q1 = 0.f;
                const float* xsb = &xs[half * 64];
#pragma unroll
                for (int i = 0; i < 64; i += 8) {
                    float4 a0 = *(const float4*)&xsb[i];
                    float4 a1 = *(const float4*)&xsb[i+4];
                    q0 += win[i+0]*a0.x + win[i+1]*a0.y + win[i+2]*a0.z + win[i+3]*a0.w;
                    q1 += win[i+4]*a1.x + win[i+5]*a1.y + win[i+6]*a1.z + win[i+7]*a1.w;
                }
                px = q0 + q1;
            }

            if (half == 1) {
                prec[j] = pr;
                if (l == 0) pin[j] = px;
            }
            __syncthreads();

            // ---- finalize phase ----
            if (half == 0) {
                if (l == 0) xtj = bin_j + px + pin[j];
                float z = xtj + pr + prec[j] + brec_j;
                float a = fast_tanh(z);
                hj += s_j * (a - hj);
                h_lds[j] = hj;
            } else if (l == L - 1 && pf) {
                xs[j] = xnext;            // half1 idle here: stage x(t+1)
            }
            __syncthreads();
        }
    }

    if (half == 0) out[(size_t)b * H + j] = hj;
}

extern "C" void kernel_launch(void* const* d_in, const int* in_sizes, int n_in,
                              void* d_out, int out_size, void* d_ws, size_t ws_size,
                              hipStream_t stream) {
    const float* x     = (const float*)d_in[0];
    const float* W_in  = (const float*)d_in[1];
    const float* b_in  = (const float*)d_in[2];
    const float* W_rec = (const float*)d_in[3];
    const float* b_rec = (const float*)d_in[4];
    const float* tau   = (const float*)d_in[5];
    const int*   numl  = (const int*)d_in[6];

    const int H = in_sizes[2];            // 256
    const int I = in_sizes[1] / H;        // 128
    const int B = out_size / H;           // 64
    const int T = in_sizes[0] / (B * I);  // 4096

    ltc_scan_kernel<<<B, 512, 0, stream>>>(x, W_in, b_in, W_rec, b_rec, tau,
                                           numl, (float*)d_out, T);
}